// Round 6
// baseline (8648.711 us; speedup 1.0000x reference)
//
#include <hip/hip_runtime.h>
#include <hip/hip_bf16.h>

#define HW 16384   // 128*128
#define WW 128

// ---------------- zero fill ----------------
__global__ void zero_kernel(float* __restrict__ p, int n) {
    int i = blockIdx.x * 256 + threadIdx.x;
    if (i < n) p[i] = 0.0f;
}

__global__ void write_code_f32(float* out, float v) {
    if (threadIdx.x == 0 && blockIdx.x == 0) out[0] = v;
}

// ---------------- weight transpose: [COUT][CIN*NTAP] -> [CIN*NTAP][COUT] ----------------
__global__ void transpose_w(const float* __restrict__ src, float* __restrict__ dst,
                            int cout, int cintap) {
    int idx = blockIdx.x * 256 + threadIdx.x;
    if (idx >= cout * cintap) return;
    int co = idx / cintap;
    int ct = idx - co * cintap;
    dst[ct * cout + co] = src[idx];
}

// ---------------- scatter voxels into dense grid + occupancy ----------------
__global__ void scatter_kernel(const float* __restrict__ vf, const int* __restrict__ coors,
                               float* __restrict__ h, float* __restrict__ occ, int n) {
    int i = blockIdx.x * 256 + threadIdx.x;
    if (i >= n) return;
    int z = coors[i * 4 + 1];
    int y = coors[i * 4 + 2];
    int x = coors[i * 4 + 3];
    int sp = z * HW + y * WW + x;
    for (int c = 0; c < 16; ++c) {
        h[c * (16 * HW) + sp] = vf[i * 16 + c];
    }
    occ[sp] = 1.0f;
}

// ---------------- pool occupancy over z: D16 -> D8 -> D4 -> D2 ----------------
__global__ void pool_occ(const float* __restrict__ o0, float* __restrict__ o1,
                         float* __restrict__ o2, float* __restrict__ o3) {
    int p = blockIdx.x * 256 + threadIdx.x;
    if (p >= HW) return;
    float a[16];
    for (int z = 0; z < 16; ++z) a[z] = o0[z * HW + p];
    for (int z = 0; z < 8; ++z) { a[z] = fmaxf(a[2 * z], a[2 * z + 1]); o1[z * HW + p] = a[z]; }
    for (int z = 0; z < 4; ++z) { a[z] = fmaxf(a[2 * z], a[2 * z + 1]); o2[z * HW + p] = a[z]; }
    for (int z = 0; z < 2; ++z) { a[z] = fmaxf(a[2 * z], a[2 * z + 1]); o3[z * HW + p] = a[z]; }
}

// ---------------- direct conv + BN + ReLU + occ mask (all-f32) ----------------
// in : [CIN][DIN][128][128] ; wT : [CIN*KD*KHW*KHW][COUT] ; occ: [DOUT][128][128]
// out: [COUT][DOUT][128][128] float
template <int CIN, int COUT, int KD, int KHW, int SZ, int DIN, int DOUT>
__global__ __launch_bounds__(128)
void conv_bn_relu(const float* __restrict__ in, const float* __restrict__ wT,
                  const float* __restrict__ gm, const float* __restrict__ bt,
                  const float* __restrict__ mn, const float* __restrict__ vr,
                  const float* __restrict__ occ, float* __restrict__ out) {
    const int row = blockIdx.x;      // zo*128 + yo
    const int zo = row >> 7;
    const int yo = row & 127;
    const int x  = threadIdx.x;
    const int PADZ = KD / 2;
    const int PADY = KHW / 2;

    float acc[COUT];
    #pragma unroll
    for (int c = 0; c < COUT; ++c) acc[c] = 0.0f;

    for (int dz = 0; dz < KD; ++dz) {
        int zi = zo * SZ + dz - PADZ;
        if (zi < 0 || zi >= DIN) continue;
        for (int dy = 0; dy < KHW; ++dy) {
            int yi = yo + dy - PADY;
            if (yi < 0 || yi >= 128) continue;
            #pragma unroll 1
            for (int cin = 0; cin < CIN; ++cin) {
                const float* inp = in + ((size_t)(cin * DIN + zi)) * HW + yi * WW;
                #pragma unroll
                for (int dx = 0; dx < KHW; ++dx) {
                    int xi = x + dx - PADY;
                    float iv = (xi >= 0 && xi < 128) ? inp[xi] : 0.0f;
                    const float* wp = wT + (size_t)((cin * KD + dz) * (KHW * KHW) + dy * KHW + dx) * COUT;
                    #pragma unroll
                    for (int c = 0; c < COUT; ++c) {
                        acc[c] = fmaf(iv, wp[c], acc[c]);
                    }
                }
            }
        }
    }

    const int osp = zo * HW + yo * WW + x;
    const float occv = occ[osp];
    #pragma unroll
    for (int c = 0; c < COUT; ++c) {
        float sc = gm[c] / sqrtf(vr[c] + 1e-5f);
        float sh = bt[c] - mn[c] * sc;
        float val = fmaf(acc[c], sc, sh);
        out[(size_t)c * DOUT * HW + osp] = fmaxf(val, 0.0f) * occv;
    }
}

extern "C" void kernel_launch(void* const* d_in, const int* in_sizes, int n_in,
                              void* d_out, int out_size, void* d_ws, size_t ws_size,
                              hipStream_t stream) {
    const float* vf    = (const float*)d_in[0];
    const int*   coors = (const int*)d_in[1];
    const float* w0    = (const float*)d_in[2];
    const float* w1    = (const float*)d_in[3];
    const float* w2    = (const float*)d_in[4];
    const float* w64   = (const float*)d_in[5];
    const float* w10   = (const float*)d_in[6];
    const float* g32   = (const float*)d_in[7];
    const float* b32   = (const float*)d_in[8];
    const float* m32   = (const float*)d_in[9];
    const float* v32   = (const float*)d_in[10];
    const float* g64   = (const float*)d_in[11];
    const float* b64   = (const float*)d_in[12];
    const float* m64   = (const float*)d_in[13];
    const float* v64   = (const float*)d_in[14];
    const int N = in_sizes[0] / 16;

    float* out_f = (float*)d_out;

    // ---- workspace layout (floats) ----
    const size_t OFF_BUFA = 0;                    // 8,388,608 (max activation 64ch x 16z... actually 32ch x 16z = 8M; 64ch x 8z = 8M)
    const size_t OFF_BUFB = 8388608;              // 8,388,608
    const size_t OFF_OCC0 = 16777216;             // 262,144
    const size_t OFF_OCC1 = OFF_OCC0 + 262144;    // 131,072
    const size_t OFF_OCC2 = OFF_OCC1 + 131072;    // 65,536
    const size_t OFF_OCC3 = OFF_OCC2 + 65536;     // 32,768
    const size_t OFF_WT0  = OFF_OCC3 + 32768;     // 13,824
    const size_t OFF_WT1  = OFF_WT0 + 13824;      // 27,648
    const size_t OFF_WT2  = OFF_WT1 + 27648;      // 55,296
    const size_t OFF_WT3  = OFF_WT2 + 55296;      // 7*110,592
    const size_t OFF_WT10 = OFF_WT3 + 7 * 110592; // 12,288
    const size_t TOTAL_FLOATS = OFF_WT10 + 12288;

    if (ws_size < TOTAL_FLOATS * sizeof(float)) {
        write_code_f32<<<dim3(1), dim3(64), 0, stream>>>(out_f, 1.0e8f);
        return;
    }

    float* ws   = (float*)d_ws;
    float* bufA = ws + OFF_BUFA;
    float* bufB = ws + OFF_BUFB;
    float* occ0 = ws + OFF_OCC0;
    float* occ1 = ws + OFF_OCC1;
    float* occ2 = ws + OFF_OCC2;
    float* occ3 = ws + OFF_OCC3;
    float* wt0  = ws + OFF_WT0;
    float* wt1  = ws + OFF_WT1;
    float* wt2  = ws + OFF_WT2;
    float* wt3  = ws + OFF_WT3;
    float* wt10 = ws + OFF_WT10;

    zero_kernel<<<dim3((16 * 16 * HW) / 256), dim3(256), 0, stream>>>(bufA, 16 * 16 * HW);
    zero_kernel<<<dim3(262144 / 256), dim3(256), 0, stream>>>(occ0, 262144);

    transpose_w<<<dim3((32 * 432 + 255) / 256), dim3(256), 0, stream>>>(w0, wt0, 32, 432);
    transpose_w<<<dim3((32 * 864 + 255) / 256), dim3(256), 0, stream>>>(w1, wt1, 32, 864);
    transpose_w<<<dim3((64 * 864 + 255) / 256), dim3(256), 0, stream>>>(w2, wt2, 64, 864);
    for (int i = 0; i < 7; ++i) {
        transpose_w<<<dim3((64 * 1728 + 255) / 256), dim3(256), 0, stream>>>(
            w64 + (size_t)i * 110592, wt3 + (size_t)i * 110592, 64, 1728);
    }
    transpose_w<<<dim3((64 * 192 + 255) / 256), dim3(256), 0, stream>>>(w10, wt10, 64, 192);

    scatter_kernel<<<dim3((N + 255) / 256), dim3(256), 0, stream>>>(vf, coors, bufA, occ0, N);
    pool_occ<<<dim3(HW / 256), dim3(256), 0, stream>>>(occ0, occ1, occ2, occ3);

    // L0: 16->32, D16
    conv_bn_relu<16, 32, 3, 3, 1, 16, 16><<<dim3(16 * 128), dim3(128), 0, stream>>>(
        bufA, wt0, g32, b32, m32, v32, occ0, bufB);
    // L1: 32->32, D16
    conv_bn_relu<32, 32, 3, 3, 1, 16, 16><<<dim3(16 * 128), dim3(128), 0, stream>>>(
        bufB, wt1, g32 + 32, b32 + 32, m32 + 32, v32 + 32, occ0, bufA);
    // L2: 32->64, stride-z 2, D16->8
    conv_bn_relu<32, 64, 3, 3, 2, 16, 8><<<dim3(8 * 128), dim3(128), 0, stream>>>(
        bufA, wt2, g64, b64, m64, v64, occ1, bufB);
    // L3..L5: 64->64, D8
    conv_bn_relu<64, 64, 3, 3, 1, 8, 8><<<dim3(8 * 128), dim3(128), 0, stream>>>(
        bufB, wt3 + 0 * 110592, g64 + 64, b64 + 64, m64 + 64, v64 + 64, occ1, bufA);
    conv_bn_relu<64, 64, 3, 3, 1, 8, 8><<<dim3(8 * 128), dim3(128), 0, stream>>>(
        bufA, wt3 + 1 * 110592, g64 + 128, b64 + 128, m64 + 128, v64 + 128, occ1, bufB);
    conv_bn_relu<64, 64, 3, 3, 1, 8, 8><<<dim3(8 * 128), dim3(128), 0, stream>>>(
        bufB, wt3 + 2 * 110592, g64 + 192, b64 + 192, m64 + 192, v64 + 192, occ1, bufA);
    // L6: 64->64, stride-z 2, D8->4
    conv_bn_relu<64, 64, 3, 3, 2, 8, 4><<<dim3(4 * 128), dim3(128), 0, stream>>>(
        bufA, wt3 + 3 * 110592, g64 + 256, b64 + 256, m64 + 256, v64 + 256, occ2, bufB);
    // L7..L9: 64->64, D4
    conv_bn_relu<64, 64, 3, 3, 1, 4, 4><<<dim3(4 * 128), dim3(128), 0, stream>>>(
        bufB, wt3 + 4 * 110592, g64 + 320, b64 + 320, m64 + 320, v64 + 320, occ2, bufA);
    conv_bn_relu<64, 64, 3, 3, 1, 4, 4><<<dim3(4 * 128), dim3(128), 0, stream>>>(
        bufA, wt3 + 5 * 110592, g64 + 384, b64 + 384, m64 + 384, v64 + 384, occ2, bufB);
    conv_bn_relu<64, 64, 3, 3, 1, 4, 4><<<dim3(4 * 128), dim3(128), 0, stream>>>(
        bufB, wt3 + 6 * 110592, g64 + 448, b64 + 448, m64 + 448, v64 + 448, occ2, bufA);
    // L10: 64->64, kernel (3,1,1), stride-z 2, D4->2, FLOAT out -> d_out
    conv_bn_relu<64, 64, 3, 1, 2, 4, 2><<<dim3(2 * 128), dim3(128), 0, stream>>>(
        bufA, wt10, g64 + 512, b64 + 512, m64 + 512, v64 + 512, occ3, out_f);
}

// Round 7
// 1205.868 us; speedup vs baseline: 7.1722x; 7.1722x over previous
//
#include <hip/hip_runtime.h>

#define HW 16384   // 128*128

typedef _Float16 half8  __attribute__((ext_vector_type(8)));
typedef _Float16 half4v __attribute__((ext_vector_type(4)));
typedef float    f32x4  __attribute__((ext_vector_type(4)));

// ---------------- zero fill (float4 granularity) ----------------
__global__ void zero4(float4* __restrict__ p, int n4) {
    int i = blockIdx.x * 256 + threadIdx.x;
    if (i < n4) p[i] = make_float4(0.f, 0.f, 0.f, 0.f);
}

__global__ void write_code_f32(float* out, float v) {
    if (threadIdx.x == 0 && blockIdx.x == 0) out[0] = v;
}

// ---------------- weight pack: OIDHW f32 -> A-fragment-ordered f16 ----------------
// dst element ((grp*NSTEPS + s)*64 + lane)*8 + j  holds W[co=grp*16+(lane&15)][k=s*32+(lane>>4)*8+j]
// where k = tap*CINp + ci, tap=(dz*KHW+dy)*KHW+dx; ci >= CINr -> 0.
__global__ void pack_w(const float* __restrict__ W, _Float16* __restrict__ dst,
                       int CINr, int CINp, int COUT, int KD, int KHW, int NSTEPS) {
    int idx = blockIdx.x * 256 + threadIdx.x;
    int total = (COUT / 16) * NSTEPS * 64;
    if (idx >= total) return;
    int lane = idx & 63;
    int s    = (idx >> 6) % NSTEPS;
    int grp  = idx / (NSTEPS * 64);
    int k0  = s * 32 + (lane >> 4) * 8;
    int t   = k0 / CINp;
    int ci0 = k0 % CINp;
    int co  = grp * 16 + (lane & 15);
    int khw2 = KHW * KHW;
    int dz = t / khw2, r = t % khw2, dy = r / KHW, dx = r % KHW;
    half8 hv;
    for (int j = 0; j < 8; ++j) {
        int ci = ci0 + j;
        float wv = (ci < CINr)
            ? W[(((size_t)co * CINr + ci) * KD + dz) * khw2 + dy * KHW + dx] : 0.0f;
        hv[j] = (_Float16)wv;
    }
    *(half8*)(dst + ((size_t)(grp * NSTEPS + s) * 64 + lane) * 8) = hv;
}

// ---------------- scatter voxels into channels-last padded f16 grid ----------------
__global__ void scatter_f16(const float* __restrict__ vf, const int* __restrict__ coors,
                            _Float16* __restrict__ act, float* __restrict__ occ, int n) {
    int i = blockIdx.x * 256 + threadIdx.x;
    if (i >= n) return;
    int z = coors[i * 4 + 1];
    int y = coors[i * 4 + 2];
    int x = coors[i * 4 + 3];
    size_t cell = ((size_t)(z * 128 + y) * 130 + (x + 1)) * 32;
    for (int c = 0; c < 16; ++c) act[cell + c] = (_Float16)vf[i * 16 + c];
    occ[z * HW + y * 128 + x] = 1.0f;
}

// ---------------- pool occupancy over z: D16 -> D8 -> D4 -> D2 ----------------
__global__ void pool_occ(const float* __restrict__ o0, float* __restrict__ o1,
                         float* __restrict__ o2, float* __restrict__ o3) {
    int p = blockIdx.x * 256 + threadIdx.x;
    if (p >= HW) return;
    float a[16];
    for (int z = 0; z < 16; ++z) a[z] = o0[z * HW + p];
    for (int z = 0; z < 8; ++z) { a[z] = fmaxf(a[2 * z], a[2 * z + 1]); o1[z * HW + p] = a[z]; }
    for (int z = 0; z < 4; ++z) { a[z] = fmaxf(a[2 * z], a[2 * z + 1]); o2[z * HW + p] = a[z]; }
    for (int z = 0; z < 2; ++z) { a[z] = fmaxf(a[2 * z], a[2 * z + 1]); o3[z * HW + p] = a[z]; }
}

// ---------------- MFMA implicit-GEMM conv + BN + ReLU + occ ----------------
// act   : [DIN][128][130][CINp] f16 (x padded by 1 each side, pads zero)
// apack : A-fragment-packed weights (see pack_w)
// out   : intermediate -> [DOUT][128][130][COUT] f16 ; FINAL -> [COUT*2][128][128] f32 (c*2+z order)
template <int CINp, int COUT, int KD, int KHW, int SZ, int DIN, int DOUT, bool FINAL>
__global__ __launch_bounds__(256)
void conv_mfma(const _Float16* __restrict__ act, const _Float16* __restrict__ apack,
               const float* __restrict__ gm, const float* __restrict__ bt,
               const float* __restrict__ mn, const float* __restrict__ vr,
               const float* __restrict__ occ, void* __restrict__ outv) {
    constexpr int WCO  = COUT / 16;          // co-groups (waves along M)
    constexpr int NXB  = (WCO == 4) ? 2 : 1; // x-blocks per row
    constexpr int PADXY = KHW / 2;
    constexpr int NSTEPS = KD * KHW * KHW * (CINp / 32);

    int bid = blockIdx.x;
    int xb = 0;
    if constexpr (NXB == 2) { xb = bid & 1; bid >>= 1; }
    const int y0 = bid & 127;
    const int z0 = bid >> 7;
    const int tid  = threadIdx.x;
    const int w    = tid >> 6;
    const int lane = tid & 63;
    const int cogrp = (WCO == 4) ? w : (w & 1);
    const int x0    = (WCO == 4) ? xb * 64 : (w >> 1) * 64;
    const int n  = lane & 15;
    const int kg = lane >> 4;
    const int lane_coff = n * CINp + kg * 8;

    const _Float16* ap = apack + (size_t)cogrp * NSTEPS * 512 + lane * 8;

    f32x4 acc[4];
    #pragma unroll
    for (int i = 0; i < 4; ++i) { acc[i][0] = 0.f; acc[i][1] = 0.f; acc[i][2] = 0.f; acc[i][3] = 0.f; }

    #pragma unroll
    for (int dz = 0; dz < KD; ++dz) {
        const int zi = z0 * SZ + dz - 1;
        if ((unsigned)zi >= (unsigned)DIN) continue;      // block-uniform skip (zero pad)
        #pragma unroll
        for (int dy = 0; dy < KHW; ++dy) {
            const int yi = y0 + dy - PADXY;
            if ((unsigned)yi >= 128u) continue;           // block-uniform skip
            #pragma unroll
            for (int dx = 0; dx < KHW; ++dx) {
                const int t = (dz * KHW + dy) * KHW + dx;
                const _Float16* bb = act
                    + ((size_t)(zi * 128 + yi) * 130 + (x0 + dx + 1 - PADXY)) * CINp + lane_coff;
                #pragma unroll
                for (int cb = 0; cb < CINp / 32; ++cb) {
                    half8 a = *(const half8*)(ap + (size_t)(t * (CINp / 32) + cb) * 512);
                    #pragma unroll
                    for (int nt = 0; nt < 4; ++nt) {
                        half8 b = *(const half8*)(bb + nt * 16 * CINp + cb * 32);
                        acc[nt] = __builtin_amdgcn_mfma_f32_16x16x32_f16(a, b, acc[nt], 0, 0, 0);
                    }
                }
            }
        }
    }

    // ---- epilogue: BN + ReLU + occ, store ----
    const int co0 = cogrp * 16 + kg * 4;
    const f32x4 gv = *(const f32x4*)(gm + co0);
    const f32x4 bv = *(const f32x4*)(bt + co0);
    const f32x4 mv = *(const f32x4*)(mn + co0);
    const f32x4 vv = *(const f32x4*)(vr + co0);
    float sc[4], sh[4];
    #pragma unroll
    for (int r = 0; r < 4; ++r) {
        sc[r] = gv[r] * __frsqrt_rn(vv[r] + 1e-5f);
        sh[r] = bv[r] - mv[r] * sc[r];
    }
    #pragma unroll
    for (int nt = 0; nt < 4; ++nt) {
        const int x = x0 + nt * 16 + n;
        const float occv = occ[z0 * HW + y0 * 128 + x];
        float v0 = fmaxf(fmaf(acc[nt][0], sc[0], sh[0]), 0.f) * occv;
        float v1 = fmaxf(fmaf(acc[nt][1], sc[1], sh[1]), 0.f) * occv;
        float v2 = fmaxf(fmaf(acc[nt][2], sc[2], sh[2]), 0.f) * occv;
        float v3 = fmaxf(fmaf(acc[nt][3], sc[3], sh[3]), 0.f) * occv;
        if constexpr (FINAL) {
            float* o = (float*)outv;
            const int sp = y0 * 128 + x;
            o[((size_t)(co0 + 0) * 2 + z0) * HW + sp] = v0;
            o[((size_t)(co0 + 1) * 2 + z0) * HW + sp] = v1;
            o[((size_t)(co0 + 2) * 2 + z0) * HW + sp] = v2;
            o[((size_t)(co0 + 3) * 2 + z0) * HW + sp] = v3;
        } else {
            _Float16* o = (_Float16*)outv;
            half4v hv;
            hv[0] = (_Float16)v0; hv[1] = (_Float16)v1;
            hv[2] = (_Float16)v2; hv[3] = (_Float16)v3;
            *(half4v*)(o + ((size_t)(z0 * 128 + y0) * 130 + (x + 1)) * COUT + co0) = hv;
        }
    }
}

extern "C" void kernel_launch(void* const* d_in, const int* in_sizes, int n_in,
                              void* d_out, int out_size, void* d_ws, size_t ws_size,
                              hipStream_t stream) {
    const float* vf    = (const float*)d_in[0];
    const int*   coors = (const int*)d_in[1];
    const float* w0    = (const float*)d_in[2];
    const float* w1    = (const float*)d_in[3];
    const float* w2    = (const float*)d_in[4];
    const float* w64   = (const float*)d_in[5];
    const float* w10   = (const float*)d_in[6];
    const float* g32   = (const float*)d_in[7];
    const float* b32   = (const float*)d_in[8];
    const float* m32   = (const float*)d_in[9];
    const float* v32   = (const float*)d_in[10];
    const float* g64   = (const float*)d_in[11];
    const float* b64   = (const float*)d_in[12];
    const float* m64   = (const float*)d_in[13];
    const float* v64   = (const float*)d_in[14];
    const int N = in_sizes[0] / 16;

    float* out_f = (float*)d_out;

    // ---- workspace layout (bytes) ----
    // 4 act buffers (all 16*128*130*32 == 8*128*130*64 f16 = 17,039,360 B)
    const size_t OFF_ACT0 = 0;
    const size_t OFF_ACT1 = 17039360;
    const size_t OFF_ACT2 = 34078720;
    const size_t OFF_ACT3 = 51118080;
    const size_t OFF_OCC0 = 68157440;   // f32 [16][HW]
    const size_t OFF_OCC1 = 69206016;   // f32 [8][HW]
    const size_t OFF_OCC2 = 69730304;   // f32 [4][HW]
    const size_t OFF_OCC3 = 69992448;   // f32 [2][HW]
    const size_t OFF_AP   = 70123520;   // packed weights f16
    const size_t TOTAL_BYTES = 71917568;

    if (ws_size < TOTAL_BYTES) {
        write_code_f32<<<dim3(1), dim3(64), 0, stream>>>(out_f, 1.0e8f);
        return;
    }

    char* wsb = (char*)d_ws;
    _Float16* ACT0 = (_Float16*)(wsb + OFF_ACT0);   // P32 A  (D4A aliases front half)
    _Float16* ACT1 = (_Float16*)(wsb + OFF_ACT1);   // P32 B  (D4B aliases front half)
    _Float16* ACT2 = (_Float16*)(wsb + OFF_ACT2);   // D8 A
    _Float16* ACT3 = (_Float16*)(wsb + OFF_ACT3);   // D8 B
    float* occ0 = (float*)(wsb + OFF_OCC0);
    float* occ1 = (float*)(wsb + OFF_OCC1);
    float* occ2 = (float*)(wsb + OFF_OCC2);
    float* occ3 = (float*)(wsb + OFF_OCC3);
    _Float16* AP = (_Float16*)(wsb + OFF_AP);

    // packed-weight offsets in f16 elements
    const size_t A0 = 0, A1 = 27648, A2 = 55296, A3 = 110592, A4 = 221184,
                 A5 = 331776, A6 = 442368, A7 = 552960, A8 = 663552,
                 A9 = 774144, A10 = 884736;

    // ---- zero act buffers + occ0 (pads & scatter target must be 0) ----
    const int ACT_N4 = 17039360 / 16;
    zero4<<<dim3((ACT_N4 + 255) / 256), dim3(256), 0, stream>>>((float4*)ACT0, ACT_N4);
    zero4<<<dim3((ACT_N4 + 255) / 256), dim3(256), 0, stream>>>((float4*)ACT1, ACT_N4);
    zero4<<<dim3((ACT_N4 + 255) / 256), dim3(256), 0, stream>>>((float4*)ACT2, ACT_N4);
    zero4<<<dim3((ACT_N4 + 255) / 256), dim3(256), 0, stream>>>((float4*)ACT3, ACT_N4);
    zero4<<<dim3((65536 + 255) / 256), dim3(256), 0, stream>>>((float4*)occ0, 65536);

    // ---- pack weights (layouts: see pack_w) ----
    auto pk = [&](const float* src, size_t dstoff, int cinr, int cinp, int cout, int kd, int khw) {
        int nsteps = kd * khw * khw * (cinp / 32);
        int total = (cout / 16) * nsteps * 64;
        pack_w<<<dim3((total + 255) / 256), dim3(256), 0, stream>>>(
            src, AP + dstoff, cinr, cinp, cout, kd, khw, nsteps);
    };
    pk(w0, A0, 16, 32, 32, 3, 3);
    pk(w1, A1, 32, 32, 32, 3, 3);
    pk(w2, A2, 32, 32, 64, 3, 3);
    for (int i = 0; i < 7; ++i)
        pk(w64 + (size_t)i * 110592, A3 + (size_t)i * 110592, 64, 64, 64, 3, 3);
    pk(w10, A10, 64, 64, 64, 3, 1);

    scatter_f16<<<dim3((N + 255) / 256), dim3(256), 0, stream>>>(vf, coors, ACT0, occ0, N);
    pool_occ<<<dim3(HW / 256), dim3(256), 0, stream>>>(occ0, occ1, occ2, occ3);

    // L0: 16(pad32)->32, D16
    conv_mfma<32, 32, 3, 3, 1, 16, 16, false><<<dim3(16 * 128), dim3(256), 0, stream>>>(
        ACT0, AP + A0, g32, b32, m32, v32, occ0, ACT1);
    // L1: 32->32, D16
    conv_mfma<32, 32, 3, 3, 1, 16, 16, false><<<dim3(16 * 128), dim3(256), 0, stream>>>(
        ACT1, AP + A1, g32 + 32, b32 + 32, m32 + 32, v32 + 32, occ0, ACT0);
    // L2: 32->64, stride-z 2, D16->8
    conv_mfma<32, 64, 3, 3, 2, 16, 8, false><<<dim3(8 * 128 * 2), dim3(256), 0, stream>>>(
        ACT0, AP + A2, g64, b64, m64, v64, occ1, ACT2);
    // P32 buffers now dead -> zero D4 alias regions (4*128*130*64 f16 = 8,519,680 B each)
    const int D4_N4 = 8519680 / 16;
    zero4<<<dim3((D4_N4 + 255) / 256), dim3(256), 0, stream>>>((float4*)ACT0, D4_N4);
    zero4<<<dim3((D4_N4 + 255) / 256), dim3(256), 0, stream>>>((float4*)ACT1, D4_N4);
    // L3..L5: 64->64, D8
    conv_mfma<64, 64, 3, 3, 1, 8, 8, false><<<dim3(8 * 128 * 2), dim3(256), 0, stream>>>(
        ACT2, AP + A3, g64 + 64, b64 + 64, m64 + 64, v64 + 64, occ1, ACT3);
    conv_mfma<64, 64, 3, 3, 1, 8, 8, false><<<dim3(8 * 128 * 2), dim3(256), 0, stream>>>(
        ACT3, AP + A4, g64 + 128, b64 + 128, m64 + 128, v64 + 128, occ1, ACT2);
    conv_mfma<64, 64, 3, 3, 1, 8, 8, false><<<dim3(8 * 128 * 2), dim3(256), 0, stream>>>(
        ACT2, AP + A5, g64 + 192, b64 + 192, m64 + 192, v64 + 192, occ1, ACT3);
    // L6: 64->64, stride-z 2, D8->4 (into D4A = ACT0 region)
    conv_mfma<64, 64, 3, 3, 2, 8, 4, false><<<dim3(4 * 128 * 2), dim3(256), 0, stream>>>(
        ACT3, AP + A6, g64 + 256, b64 + 256, m64 + 256, v64 + 256, occ2, ACT0);
    // L7..L9: 64->64, D4
    conv_mfma<64, 64, 3, 3, 1, 4, 4, false><<<dim3(4 * 128 * 2), dim3(256), 0, stream>>>(
        ACT0, AP + A7, g64 + 320, b64 + 320, m64 + 320, v64 + 320, occ2, ACT1);
    conv_mfma<64, 64, 3, 3, 1, 4, 4, false><<<dim3(4 * 128 * 2), dim3(256), 0, stream>>>(
        ACT1, AP + A8, g64 + 384, b64 + 384, m64 + 384, v64 + 384, occ2, ACT0);
    conv_mfma<64, 64, 3, 3, 1, 4, 4, false><<<dim3(4 * 128 * 2), dim3(256), 0, stream>>>(
        ACT0, AP + A9, g64 + 448, b64 + 448, m64 + 448, v64 + 448, occ2, ACT1);
    // L10: 64->64, kernel (3,1,1), stride-z 2, D4->2, f32 out -> d_out
    conv_mfma<64, 64, 3, 1, 2, 4, 2, true><<<dim3(2 * 128 * 2), dim3(256), 0, stream>>>(
        ACT1, AP + A10, g64 + 512, b64 + 512, m64 + 512, v64 + 512, occ3, out_f);
}

// Round 8
// 763.155 us; speedup vs baseline: 11.3328x; 1.5801x over previous
//
#include <hip/hip_runtime.h>

#define HW 16384   // 128*128

typedef _Float16 half8  __attribute__((ext_vector_type(8)));
typedef _Float16 half4v __attribute__((ext_vector_type(4)));
typedef float    f32x4  __attribute__((ext_vector_type(4)));

// ---------------- zero fill (float4 granularity) ----------------
__global__ void zero4(float4* __restrict__ p, int n4) {
    int i = blockIdx.x * 256 + threadIdx.x;
    if (i < n4) p[i] = make_float4(0.f, 0.f, 0.f, 0.f);
}

__global__ void write_code_f32(float* out, float v) {
    if (threadIdx.x == 0 && blockIdx.x == 0) out[0] = v;
}

// ---------------- weight pack: OIDHW f32 -> A-fragment-ordered f16 ----------------
// dst[((grp*NSTEPS+s)*64+lane)*8+j] = W[co=grp*16+(lane&15)][k=s*32+(lane>>4)*8+j]
// k = tap*CINp + ci, tap = (dz*KHW+dy)*KHW+dx ; ci >= CINr -> 0
__global__ void pack_w(const float* __restrict__ W, _Float16* __restrict__ dst,
                       int CINr, int CINp, int COUT, int KD, int KHW, int NSTEPS) {
    int idx = blockIdx.x * 256 + threadIdx.x;
    int total = (COUT / 16) * NSTEPS * 64;
    if (idx >= total) return;
    int lane = idx & 63;
    int s    = (idx >> 6) % NSTEPS;
    int grp  = idx / (NSTEPS * 64);
    int k0  = s * 32 + (lane >> 4) * 8;
    int t   = k0 / CINp;
    int ci0 = k0 % CINp;
    int co  = grp * 16 + (lane & 15);
    int khw2 = KHW * KHW;
    int dz = t / khw2, r = t % khw2, dy = r / KHW, dx = r % KHW;
    half8 hv;
    for (int j = 0; j < 8; ++j) {
        int ci = ci0 + j;
        float wv = (ci < CINr)
            ? W[(((size_t)co * CINr + ci) * KD + dz) * khw2 + dy * KHW + dx] : 0.0f;
        hv[j] = (_Float16)wv;
    }
    *(half8*)(dst + ((size_t)(grp * NSTEPS + s) * 64 + lane) * 8) = hv;
}

// ---------------- scatter voxels into [z][130][130][32] f16 grid ----------------
__global__ void scatter_f16(const float* __restrict__ vf, const int* __restrict__ coors,
                            _Float16* __restrict__ act, unsigned char* __restrict__ occ, int n) {
    int i = blockIdx.x * 256 + threadIdx.x;
    if (i >= n) return;
    int z = coors[i * 4 + 1];
    int y = coors[i * 4 + 2];
    int x = coors[i * 4 + 3];
    size_t cell = ((size_t)(z * 130 + (y + 1)) * 130 + (x + 1)) * 32;
    for (int c = 0; c < 16; ++c) act[cell + c] = (_Float16)vf[i * 16 + c];
    occ[z * HW + y * 128 + x] = 1;
}

// ---------------- pool occupancy (u8) over z: D16 -> D8 -> D4 -> D2 ----------------
__global__ void pool_occ(const unsigned char* __restrict__ o0, unsigned char* __restrict__ o1,
                         unsigned char* __restrict__ o2, unsigned char* __restrict__ o3) {
    int p = blockIdx.x * 256 + threadIdx.x;
    if (p >= HW) return;
    unsigned char a[16];
    for (int z = 0; z < 16; ++z) a[z] = o0[z * HW + p];
    for (int z = 0; z < 8; ++z) { a[z] = a[2 * z] | a[2 * z + 1]; o1[z * HW + p] = a[z]; }
    for (int z = 0; z < 4; ++z) { a[z] = a[2 * z] | a[2 * z + 1]; o2[z * HW + p] = a[z]; }
    for (int z = 0; z < 2; ++z) { a[z] = a[2 * z] | a[2 * z + 1]; o3[z * HW + p] = a[z]; }
}

// ---------------- MFMA implicit-GEMM conv + BN + ReLU + occ ----------------
// act : [DIN][130][130][CINp] f16, y/x padded by 1, pads zero
// out : intermediate [DOUT][130][130][COUT] f16 ; FINAL [COUT*2][128][128] f32
// wave tile: 32 couts x 64 px. COUT=64: block=256thr, cg2=w&1, x0=(w>>1)*64.
//            COUT=32: block=128thr, cg2=0,   x0=w*64.
template <int CINp, int COUT, int KD, int KHW, int SZ, int DIN, int DOUT, bool FINAL>
__global__ __launch_bounds__(256)
void conv_mfma(const _Float16* __restrict__ act, const _Float16* __restrict__ apack,
               const float* __restrict__ gm, const float* __restrict__ bt,
               const float* __restrict__ mn, const float* __restrict__ vr,
               const unsigned char* __restrict__ occ, void* __restrict__ outv) {
    constexpr int PADXY  = KHW / 2;
    constexpr int NSTEPS = KD * KHW * KHW * (CINp / 32);
    constexpr int CB     = CINp / 32;

    const int bid = blockIdx.x;
    const int y0 = bid & 127;
    const int z0 = bid >> 7;
    const int tid  = threadIdx.x;
    const int w    = tid >> 6;
    const int lane = tid & 63;
    const int cg2 = (COUT == 64) ? (w & 1) : 0;
    const int x0  = (COUT == 64) ? (w >> 1) * 64 : w * 64;
    const int n  = lane & 15;
    const int kg = lane >> 4;
    const int lane_coff = n * CINp + kg * 8;

    const _Float16* ap0 = apack + ((size_t)(cg2 * 2 + 0) * NSTEPS * 64 + lane) * 8;
    const _Float16* ap1 = apack + ((size_t)(cg2 * 2 + 1) * NSTEPS * 64 + lane) * 8;

    f32x4 acc[2][4];
    #pragma unroll
    for (int m = 0; m < 2; ++m)
        #pragma unroll
        for (int t = 0; t < 4; ++t) { acc[m][t][0] = 0.f; acc[m][t][1] = 0.f; acc[m][t][2] = 0.f; acc[m][t][3] = 0.f; }

    // dz bounds: zi = z0*SZ + dz - 1 in [0, DIN)
    const int zb = z0 * SZ;
    const int dzlo = (zb == 0) ? 1 : 0;
    const int dzhi = (zb + KD - 1 > DIN) ? (KD - 1) : KD;

    for (int dz = dzlo; dz < dzhi; ++dz) {
        const int zi = zb + dz - 1;
        const _Float16* bz = act + (size_t)zi * (130 * 130 * CINp)
            + ((size_t)(y0 + 1 - PADXY) * 130 + (x0 + 1 - PADXY)) * CINp + lane_coff;
        const _Float16* az0 = ap0 + (size_t)dz * (KHW * KHW * CB) * 512;
        const _Float16* az1 = ap1 + (size_t)dz * (KHW * KHW * CB) * 512;
        #pragma unroll
        for (int dy = 0; dy < KHW; ++dy) {
            #pragma unroll
            for (int dx = 0; dx < KHW; ++dx) {
                #pragma unroll
                for (int cb = 0; cb < CB; ++cb) {
                    const int s = (dy * KHW + dx) * CB + cb;
                    half8 a0 = *(const half8*)(az0 + (size_t)s * 512);
                    half8 a1 = *(const half8*)(az1 + (size_t)s * 512);
                    const _Float16* bp = bz + ((dy * 130 + dx) * CINp + cb * 32);
                    #pragma unroll
                    for (int nt = 0; nt < 4; ++nt) {
                        half8 b = *(const half8*)(bp + nt * 16 * CINp);
                        acc[0][nt] = __builtin_amdgcn_mfma_f32_16x16x32_f16(a0, b, acc[0][nt], 0, 0, 0);
                        acc[1][nt] = __builtin_amdgcn_mfma_f32_16x16x32_f16(a1, b, acc[1][nt], 0, 0, 0);
                    }
                }
            }
        }
    }

    // ---- epilogue: BN + ReLU + occ, store ----
    #pragma unroll
    for (int m = 0; m < 2; ++m) {
        const int co0 = (cg2 * 2 + m) * 16 + kg * 4;
        const f32x4 gv = *(const f32x4*)(gm + co0);
        const f32x4 bv = *(const f32x4*)(bt + co0);
        const f32x4 mv = *(const f32x4*)(mn + co0);
        const f32x4 vv = *(const f32x4*)(vr + co0);
        float sc[4], sh[4];
        #pragma unroll
        for (int r = 0; r < 4; ++r) {
            sc[r] = gv[r] * __frsqrt_rn(vv[r] + 1e-5f);
            sh[r] = bv[r] - mv[r] * sc[r];
        }
        #pragma unroll
        for (int nt = 0; nt < 4; ++nt) {
            const int x = x0 + nt * 16 + n;
            const float occv = (float)occ[z0 * HW + y0 * 128 + x];
            float v0 = fmaxf(fmaf(acc[m][nt][0], sc[0], sh[0]), 0.f) * occv;
            float v1 = fmaxf(fmaf(acc[m][nt][1], sc[1], sh[1]), 0.f) * occv;
            float v2 = fmaxf(fmaf(acc[m][nt][2], sc[2], sh[2]), 0.f) * occv;
            float v3 = fmaxf(fmaf(acc[m][nt][3], sc[3], sh[3]), 0.f) * occv;
            if constexpr (FINAL) {
                float* o = (float*)outv;
                const int sp = y0 * 128 + x;
                o[((size_t)(co0 + 0) * 2 + z0) * HW + sp] = v0;
                o[((size_t)(co0 + 1) * 2 + z0) * HW + sp] = v1;
                o[((size_t)(co0 + 2) * 2 + z0) * HW + sp] = v2;
                o[((size_t)(co0 + 3) * 2 + z0) * HW + sp] = v3;
            } else {
                _Float16* o = (_Float16*)outv;
                half4v hv;
                hv[0] = (_Float16)v0; hv[1] = (_Float16)v1;
                hv[2] = (_Float16)v2; hv[3] = (_Float16)v3;
                *(half4v*)(o + ((size_t)(z0 * 130 + (y0 + 1)) * 130 + (x + 1)) * COUT + co0) = hv;
            }
        }
    }
}

extern "C" void kernel_launch(void* const* d_in, const int* in_sizes, int n_in,
                              void* d_out, int out_size, void* d_ws, size_t ws_size,
                              hipStream_t stream) {
    const float* vf    = (const float*)d_in[0];
    const int*   coors = (const int*)d_in[1];
    const float* w0    = (const float*)d_in[2];
    const float* w1    = (const float*)d_in[3];
    const float* w2    = (const float*)d_in[4];
    const float* w64   = (const float*)d_in[5];
    const float* w10   = (const float*)d_in[6];
    const float* g32   = (const float*)d_in[7];
    const float* b32   = (const float*)d_in[8];
    const float* m32   = (const float*)d_in[9];
    const float* v32   = (const float*)d_in[10];
    const float* g64   = (const float*)d_in[11];
    const float* b64   = (const float*)d_in[12];
    const float* m64   = (const float*)d_in[13];
    const float* v64   = (const float*)d_in[14];
    const int N = in_sizes[0] / 16;

    float* out_f = (float*)d_out;

    // ---- workspace layout (bytes) ----
    // R0/R1: [16][130][130][32] f16 = 17,305,600 (front 8,652,800 re-used as D4 [4][130][130][64])
    // R2/R3: [8][130][130][64]  f16 = 17,305,600
    const size_t R0 = 0;
    const size_t R1 = 17305600;
    const size_t R2 = 34611200;
    const size_t R3 = 51916800;
    const size_t OFF_OCC0 = 69222400;   // u8 [16][HW]
    const size_t OFF_OCC1 = 69484544;   // u8 [8][HW]
    const size_t OFF_OCC2 = 69615616;   // u8 [4][HW]
    const size_t OFF_OCC3 = 69681152;   // u8 [2][HW]
    const size_t OFF_AP   = 69713920;   // f16 packed weights (897,024 el)
    const size_t TOTAL_BYTES = 71507968;

    if (ws_size < TOTAL_BYTES) {
        write_code_f32<<<dim3(1), dim3(64), 0, stream>>>(out_f, 1.0e8f);
        return;
    }

    char* wsb = (char*)d_ws;
    _Float16* A0p = (_Float16*)(wsb + R0);
    _Float16* A1p = (_Float16*)(wsb + R1);
    _Float16* A2p = (_Float16*)(wsb + R2);
    _Float16* A3p = (_Float16*)(wsb + R3);
    unsigned char* occ0 = (unsigned char*)(wsb + OFF_OCC0);
    unsigned char* occ1 = (unsigned char*)(wsb + OFF_OCC1);
    unsigned char* occ2 = (unsigned char*)(wsb + OFF_OCC2);
    unsigned char* occ3 = (unsigned char*)(wsb + OFF_OCC3);
    _Float16* AP = (_Float16*)(wsb + OFF_AP);

    // packed-weight offsets (f16 elements)
    const size_t W_A0 = 0, W_A1 = 27648, W_A2 = 55296, W_A3 = 110592, W_A10 = 884736;

    // ---- zero act regions + occ0 (one contiguous span: 0 .. occ0 end) ----
    {
        const int n4 = (int)((OFF_OCC1) / 16);   // 69,484,544 / 16
        zero4<<<dim3((n4 + 255) / 256), dim3(256), 0, stream>>>((float4*)wsb, n4);
    }

    // ---- pack weights ----
    auto pk = [&](const float* src, size_t dstoff, int cinr, int cinp, int cout, int kd, int khw) {
        int nsteps = kd * khw * khw * (cinp / 32);
        int total = (cout / 16) * nsteps * 64;
        pack_w<<<dim3((total + 255) / 256), dim3(256), 0, stream>>>(
            src, AP + dstoff, cinr, cinp, cout, kd, khw, nsteps);
    };
    pk(w0, W_A0, 16, 32, 32, 3, 3);
    pk(w1, W_A1, 32, 32, 32, 3, 3);
    pk(w2, W_A2, 32, 32, 64, 3, 3);
    for (int i = 0; i < 7; ++i)
        pk(w64 + (size_t)i * 110592, W_A3 + (size_t)i * 110592, 64, 64, 64, 3, 3);
    pk(w10, W_A10, 64, 64, 64, 3, 1);

    scatter_f16<<<dim3((N + 255) / 256), dim3(256), 0, stream>>>(vf, coors, A0p, occ0, N);
    pool_occ<<<dim3(HW / 256), dim3(256), 0, stream>>>(occ0, occ1, occ2, occ3);

    // L0: 16(pad32)->32, D16
    conv_mfma<32, 32, 3, 3, 1, 16, 16, false><<<dim3(16 * 128), dim3(128), 0, stream>>>(
        A0p, AP + W_A0, g32, b32, m32, v32, occ0, A1p);
    // L1: 32->32, D16
    conv_mfma<32, 32, 3, 3, 1, 16, 16, false><<<dim3(16 * 128), dim3(128), 0, stream>>>(
        A1p, AP + W_A1, g32 + 32, b32 + 32, m32 + 32, v32 + 32, occ0, A0p);
    // L2: 32->64, stride-z 2, D16->8
    conv_mfma<32, 64, 3, 3, 2, 16, 8, false><<<dim3(8 * 128), dim3(256), 0, stream>>>(
        A0p, AP + W_A2, g64, b64, m64, v64, occ1, A2p);
    // P32 regions dead -> zero the D4 alias fronts ([4][130][130][64] = 8,652,800 B)
    {
        const int n4 = 8652800 / 16;
        zero4<<<dim3((n4 + 255) / 256), dim3(256), 0, stream>>>((float4*)A0p, n4);
        zero4<<<dim3((n4 + 255) / 256), dim3(256), 0, stream>>>((float4*)A1p, n4);
    }
    // L3..L5: 64->64, D8
    conv_mfma<64, 64, 3, 3, 1, 8, 8, false><<<dim3(8 * 128), dim3(256), 0, stream>>>(
        A2p, AP + W_A3 + 0 * 110592, g64 + 64, b64 + 64, m64 + 64, v64 + 64, occ1, A3p);
    conv_mfma<64, 64, 3, 3, 1, 8, 8, false><<<dim3(8 * 128), dim3(256), 0, stream>>>(
        A3p, AP + W_A3 + 1 * 110592, g64 + 128, b64 + 128, m64 + 128, v64 + 128, occ1, A2p);
    conv_mfma<64, 64, 3, 3, 1, 8, 8, false><<<dim3(8 * 128), dim3(256), 0, stream>>>(
        A2p, AP + W_A3 + 2 * 110592, g64 + 192, b64 + 192, m64 + 192, v64 + 192, occ1, A3p);
    // L6: 64->64, stride-z 2, D8->4 (out = D4A in R0)
    conv_mfma<64, 64, 3, 3, 2, 8, 4, false><<<dim3(4 * 128), dim3(256), 0, stream>>>(
        A3p, AP + W_A3 + 3 * 110592, g64 + 256, b64 + 256, m64 + 256, v64 + 256, occ2, A0p);
    // L7..L9: 64->64, D4
    conv_mfma<64, 64, 3, 3, 1, 4, 4, false><<<dim3(4 * 128), dim3(256), 0, stream>>>(
        A0p, AP + W_A3 + 4 * 110592, g64 + 320, b64 + 320, m64 + 320, v64 + 320, occ2, A1p);
    conv_mfma<64, 64, 3, 3, 1, 4, 4, false><<<dim3(4 * 128), dim3(256), 0, stream>>>(
        A1p, AP + W_A3 + 5 * 110592, g64 + 384, b64 + 384, m64 + 384, v64 + 384, occ2, A0p);
    conv_mfma<64, 64, 3, 3, 1, 4, 4, false><<<dim3(4 * 128), dim3(256), 0, stream>>>(
        A0p, AP + W_A3 + 6 * 110592, g64 + 448, b64 + 448, m64 + 448, v64 + 448, occ2, A1p);
    // L10: 64->64, kernel (3,1,1), stride-z 2, D4->2, f32 out -> d_out
    conv_mfma<64, 64, 3, 1, 2, 4, 2, true><<<dim3(2 * 128), dim3(256), 0, stream>>>(
        A1p, AP + W_A10, g64 + 512, b64 + 512, m64 + 512, v64 + 512, occ3, out_f);
}

// Round 10
// 377.461 us; speedup vs baseline: 22.9129x; 2.0218x over previous
//
#include <hip/hip_runtime.h>

#define HW 16384   // 128*128

typedef _Float16 half8  __attribute__((ext_vector_type(8)));
typedef _Float16 half4v __attribute__((ext_vector_type(4)));
typedef float    f32x4  __attribute__((ext_vector_type(4)));

// ---------------- zero fill (float4 granularity) ----------------
__global__ void zero4(float4* __restrict__ p, int n4) {
    int i = blockIdx.x * 256 + threadIdx.x;
    if (i < n4) p[i] = make_float4(0.f, 0.f, 0.f, 0.f);
}

__global__ void write_code_f32(float* out, float v) {
    if (threadIdx.x == 0 && blockIdx.x == 0) out[0] = v;
}

// ---------------- weight pack: OIDHW f32 -> A-fragment-ordered f16 ----------------
// dst[((grp*NSTEPS+s)*64+lane)*8+j] = W[co=grp*16+(lane&15)][k=s*32+(lane>>4)*8+j]
// k = tap*CINp + ci, tap = (dz*KHW+dy)*KHW+dx ; ci >= CINr -> 0
__global__ void pack_w(const float* __restrict__ W, _Float16* __restrict__ dst,
                       int CINr, int CINp, int COUT, int KD, int KHW, int NSTEPS) {
    int idx = blockIdx.x * 256 + threadIdx.x;
    int total = (COUT / 16) * NSTEPS * 64;
    if (idx >= total) return;
    int lane = idx & 63;
    int s    = (idx >> 6) % NSTEPS;
    int grp  = idx / (NSTEPS * 64);
    int k0  = s * 32 + (lane >> 4) * 8;
    int t   = k0 / CINp;
    int ci0 = k0 % CINp;
    int co  = grp * 16 + (lane & 15);
    int khw2 = KHW * KHW;
    int dz = t / khw2, r = t % khw2, dy = r / KHW, dx = r % KHW;
    half8 hv;
    for (int j = 0; j < 8; ++j) {
        int ci = ci0 + j;
        float wv = (ci < CINr)
            ? W[(((size_t)co * CINr + ci) * KD + dz) * khw2 + dy * KHW + dx] : 0.0f;
        hv[j] = (_Float16)wv;
    }
    *(half8*)(dst + ((size_t)(grp * NSTEPS + s) * 64 + lane) * 8) = hv;
}

// ---------------- scatter voxels into [z][130][130][32] f16 grid ----------------
__global__ void scatter_f16(const float* __restrict__ vf, const int* __restrict__ coors,
                            _Float16* __restrict__ act, unsigned char* __restrict__ occ, int n) {
    int i = blockIdx.x * 256 + threadIdx.x;
    if (i >= n) return;
    int z = coors[i * 4 + 1];
    int y = coors[i * 4 + 2];
    int x = coors[i * 4 + 3];
    size_t cell = ((size_t)(z * 130 + (y + 1)) * 130 + (x + 1)) * 32;
    for (int c = 0; c < 16; ++c) act[cell + c] = (_Float16)vf[i * 16 + c];
    occ[z * HW + y * 128 + x] = 1;
}

// ---------------- pool occupancy (u8) over z: D16 -> D8 -> D4 -> D2 ----------------
__global__ void pool_occ(const unsigned char* __restrict__ o0, unsigned char* __restrict__ o1,
                         unsigned char* __restrict__ o2, unsigned char* __restrict__ o3) {
    int p = blockIdx.x * 256 + threadIdx.x;
    if (p >= HW) return;
    unsigned char a[16];
    for (int z = 0; z < 16; ++z) a[z] = o0[z * HW + p];
    for (int z = 0; z < 8; ++z) { a[z] = a[2 * z] | a[2 * z + 1]; o1[z * HW + p] = a[z]; }
    for (int z = 0; z < 4; ++z) { a[z] = a[2 * z] | a[2 * z + 1]; o2[z * HW + p] = a[z]; }
    for (int z = 0; z < 2; ++z) { a[z] = a[2 * z] | a[2 * z + 1]; o3[z * HW + p] = a[z]; }
}

// ---------------- MFMA implicit-GEMM conv + BN + ReLU + occ, LDS-staged ----------------
// act : [DIN][130][130][CINp] f16, y/x padded by 1, pads zero
// out : intermediate [DOUT][130][130][COUT] f16 ; FINAL [COUT*2][128][128] f32
// block: 4 waves = 2 output rows x 128 x, each wave = ALL COUT x 64 px.
template <int CINp, int COUT, int KD, int KHW, int SZ, int DIN, int DOUT, bool FINAL>
__global__ __launch_bounds__(256, 2)
void conv_mfma(const _Float16* __restrict__ act, const _Float16* __restrict__ apack,
               const float* __restrict__ gm, const float* __restrict__ bt,
               const float* __restrict__ mn, const float* __restrict__ vr,
               const unsigned char* __restrict__ occ, void* __restrict__ outv) {
    constexpr int PADXY  = KHW / 2;
    constexpr int CB     = CINp / 32;           // 32-k blocks per tap
    constexpr int MG     = COUT / 16;           // co-groups per wave
    constexpr int NSTEPS = KD * KHW * KHW * CB; // total K-steps (for A indexing)
    constexpr int PADC   = CINp + 8;            // padded channel stride in LDS
    constexpr int GPC    = CINp / 8;            // 16B granules per cell
    constexpr int NGRAN  = 4 * 130 * GPC;       // granules per stripe
    constexpr int NITER  = (NGRAN + 255) / 256;
    constexpr int OFS    = 1 - PADXY;           // tap offset correction

    __shared__ _Float16 smem[4 * 130 * PADC];

    const int bid = blockIdx.x;
    const int yp = bid & 63;
    const int z0 = bid >> 6;
    const int y0 = yp * 2;
    const int tid  = threadIdx.x;
    const int w    = tid >> 6;
    const int lane = tid & 63;
    const int ylocal = w >> 1;       // 0..1
    const int x0w    = (w & 1) * 64; // 0 or 64
    const int n  = lane & 15;
    const int kg = lane >> 4;

    f32x4 acc[MG][4];
    #pragma unroll
    for (int m = 0; m < MG; ++m)
        #pragma unroll
        for (int t = 0; t < 4; ++t) { acc[m][t][0] = 0.f; acc[m][t][1] = 0.f; acc[m][t][2] = 0.f; acc[m][t][3] = 0.f; }

    const int zb = z0 * SZ;
    const int dzlo = (zb == 0) ? 1 : 0;
    const int dzhi = (zb + KD - 1 > DIN) ? (KD - 1) : KD;

    for (int dz = dzlo; dz < dzhi; ++dz) {
        const int zi = zb + dz - 1;
        __syncthreads();   // protect previous iteration's LDS reads
        // ---- stage 4-row stripe (padded rows y0..y0+3, all 130 cols) ----
        const _Float16* src = act + (size_t)(zi * 130 + y0) * (130 * CINp);
        #pragma unroll
        for (int it = 0; it < NITER; ++it) {
            int g = it * 256 + tid;
            if (g < NGRAN) {
                float4 v = *(const float4*)(src + (size_t)g * 8);
                *(float4*)(smem + (g / GPC) * PADC + (g % GPC) * 8) = v;
            }
        }
        __syncthreads();
        // ---- K-loop over taps (straight-line) ----
        #pragma unroll
        for (int dy = 0; dy < KHW; ++dy) {
            #pragma unroll
            for (int dx = 0; dx < KHW; ++dx) {
                #pragma unroll
                for (int cb = 0; cb < CB; ++cb) {
                    const int sabs = dz * (KHW * KHW * CB) + (dy * KHW + dx) * CB + cb;
                    half8 a[MG];
                    #pragma unroll
                    for (int mg = 0; mg < MG; ++mg)
                        a[mg] = *(const half8*)(apack + ((size_t)(mg * NSTEPS + sabs) * 64 + lane) * 8);
                    const _Float16* bp = smem
                        + ((ylocal + dy + OFS) * 130 + x0w + n + dx + OFS) * PADC + cb * 32 + kg * 8;
                    #pragma unroll
                    for (int nt = 0; nt < 4; ++nt) {
                        half8 b = *(const half8*)(bp + nt * 16 * PADC);
                        #pragma unroll
                        for (int mg = 0; mg < MG; ++mg)
                            acc[mg][nt] = __builtin_amdgcn_mfma_f32_16x16x32_f16(a[mg], b, acc[mg][nt], 0, 0, 0);
                    }
                }
            }
        }
    }

    // ---- epilogue: BN + ReLU + occ, store ----
    const int yo = y0 + ylocal;
    #pragma unroll
    for (int mg = 0; mg < MG; ++mg) {
        const int co0 = mg * 16 + kg * 4;
        const f32x4 gv = *(const f32x4*)(gm + co0);
        const f32x4 bv = *(const f32x4*)(bt + co0);
        const f32x4 mv = *(const f32x4*)(mn + co0);
        const f32x4 vv = *(const f32x4*)(vr + co0);
        float sc[4], sh[4];
        #pragma unroll
        for (int r = 0; r < 4; ++r) {
            sc[r] = gv[r] * __frsqrt_rn(vv[r] + 1e-5f);
            sh[r] = bv[r] - mv[r] * sc[r];
        }
        #pragma unroll
        for (int nt = 0; nt < 4; ++nt) {
            const int x = x0w + nt * 16 + n;
            const float occv = (float)occ[z0 * HW + yo * 128 + x];
            float v0 = fmaxf(fmaf(acc[mg][nt][0], sc[0], sh[0]), 0.f) * occv;
            float v1 = fmaxf(fmaf(acc[mg][nt][1], sc[1], sh[1]), 0.f) * occv;
            float v2 = fmaxf(fmaf(acc[mg][nt][2], sc[2], sh[2]), 0.f) * occv;
            float v3 = fmaxf(fmaf(acc[mg][nt][3], sc[3], sh[3]), 0.f) * occv;
            if constexpr (FINAL) {
                float* o = (float*)outv;
                const int sp = yo * 128 + x;
                o[((size_t)(co0 + 0) * 2 + z0) * HW + sp] = v0;
                o[((size_t)(co0 + 1) * 2 + z0) * HW + sp] = v1;
                o[((size_t)(co0 + 2) * 2 + z0) * HW + sp] = v2;
                o[((size_t)(co0 + 3) * 2 + z0) * HW + sp] = v3;
            } else {
                _Float16* o = (_Float16*)outv;
                half4v hv;
                hv[0] = (_Float16)v0; hv[1] = (_Float16)v1;
                hv[2] = (_Float16)v2; hv[3] = (_Float16)v3;
                *(half4v*)(o + ((size_t)(z0 * 130 + (yo + 1)) * 130 + (x + 1)) * COUT + co0) = hv;
            }
        }
    }
}

extern "C" void kernel_launch(void* const* d_in, const int* in_sizes, int n_in,
                              void* d_out, int out_size, void* d_ws, size_t ws_size,
                              hipStream_t stream) {
    const float* vf    = (const float*)d_in[0];
    const int*   coors = (const int*)d_in[1];
    const float* w0    = (const float*)d_in[2];
    const float* w1    = (const float*)d_in[3];
    const float* w2    = (const float*)d_in[4];
    const float* w64   = (const float*)d_in[5];
    const float* w10   = (const float*)d_in[6];
    const float* g32   = (const float*)d_in[7];
    const float* b32   = (const float*)d_in[8];
    const float* m32   = (const float*)d_in[9];
    const float* v32   = (const float*)d_in[10];
    const float* g64   = (const float*)d_in[11];
    const float* b64   = (const float*)d_in[12];
    const float* m64   = (const float*)d_in[13];
    const float* v64   = (const float*)d_in[14];
    const int N = in_sizes[0] / 16;

    float* out_f = (float*)d_out;

    // ---- workspace layout (bytes) ----
    const size_t R0 = 0;
    const size_t R1 = 17305600;
    const size_t R2 = 34611200;
    const size_t R3 = 51916800;
    const size_t OFF_OCC0 = 69222400;   // u8 [16][HW]
    const size_t OFF_OCC1 = 69484544;   // u8 [8][HW]
    const size_t OFF_OCC2 = 69615616;   // u8 [4][HW]
    const size_t OFF_OCC3 = 69681152;   // u8 [2][HW]
    const size_t OFF_AP   = 69713920;   // f16 packed weights
    const size_t TOTAL_BYTES = 71507968;

    if (ws_size < TOTAL_BYTES) {
        write_code_f32<<<dim3(1), dim3(64), 0, stream>>>(out_f, 1.0e8f);
        return;
    }

    char* wsb = (char*)d_ws;
    _Float16* A0p = (_Float16*)(wsb + R0);
    _Float16* A1p = (_Float16*)(wsb + R1);
    _Float16* A2p = (_Float16*)(wsb + R2);
    _Float16* A3p = (_Float16*)(wsb + R3);
    unsigned char* occ0 = (unsigned char*)(wsb + OFF_OCC0);
    unsigned char* occ1 = (unsigned char*)(wsb + OFF_OCC1);
    unsigned char* occ2 = (unsigned char*)(wsb + OFF_OCC2);
    unsigned char* occ3 = (unsigned char*)(wsb + OFF_OCC3);
    _Float16* AP = (_Float16*)(wsb + OFF_AP);

    const size_t W_A0 = 0, W_A1 = 27648, W_A2 = 55296, W_A3 = 110592, W_A10 = 884736;

    // zero act regions + occ0 (contiguous)
    {
        const int n4 = (int)(OFF_OCC1 / 16);
        zero4<<<dim3((n4 + 255) / 256), dim3(256), 0, stream>>>((float4*)wsb, n4);
    }

    auto pk = [&](const float* src, size_t dstoff, int cinr, int cinp, int cout, int kd, int khw) {
        int nsteps = kd * khw * khw * (cinp / 32);
        int total = (cout / 16) * nsteps * 64;
        pack_w<<<dim3((total + 255) / 256), dim3(256), 0, stream>>>(
            src, AP + dstoff, cinr, cinp, cout, kd, khw, nsteps);
    };
    pk(w0, W_A0, 16, 32, 32, 3, 3);
    pk(w1, W_A1, 32, 32, 32, 3, 3);
    pk(w2, W_A2, 32, 32, 64, 3, 3);
    for (int i = 0; i < 7; ++i)
        pk(w64 + (size_t)i * 110592, W_A3 + (size_t)i * 110592, 64, 64, 64, 3, 3);
    pk(w10, W_A10, 64, 64, 64, 3, 1);

    scatter_f16<<<dim3((N + 255) / 256), dim3(256), 0, stream>>>(vf, coors, A0p, occ0, N);
    pool_occ<<<dim3(HW / 256), dim3(256), 0, stream>>>(occ0, occ1, occ2, occ3);

    // L0: 16(pad32)->32, D16
    conv_mfma<32, 32, 3, 3, 1, 16, 16, false><<<dim3(16 * 64), dim3(256), 0, stream>>>(
        A0p, AP + W_A0, g32, b32, m32, v32, occ0, A1p);
    // L1: 32->32, D16
    conv_mfma<32, 32, 3, 3, 1, 16, 16, false><<<dim3(16 * 64), dim3(256), 0, stream>>>(
        A1p, AP + W_A1, g32 + 32, b32 + 32, m32 + 32, v32 + 32, occ0, A0p);
    // L2: 32->64, stride-z 2, D16->8
    conv_mfma<32, 64, 3, 3, 2, 16, 8, false><<<dim3(8 * 64), dim3(256), 0, stream>>>(
        A0p, AP + W_A2, g64, b64, m64, v64, occ1, A2p);
    // P32 regions dead -> zero the D4 alias fronts ([4][130][130][64] = 8,652,800 B)
    {
        const int n4 = 8652800 / 16;
        zero4<<<dim3((n4 + 255) / 256), dim3(256), 0, stream>>>((float4*)A0p, n4);
        zero4<<<dim3((n4 + 255) / 256), dim3(256), 0, stream>>>((float4*)A1p, n4);
    }
    // L3..L5: 64->64, D8
    conv_mfma<64, 64, 3, 3, 1, 8, 8, false><<<dim3(8 * 64), dim3(256), 0, stream>>>(
        A2p, AP + W_A3 + 0 * 110592, g64 + 64, b64 + 64, m64 + 64, v64 + 64, occ1, A3p);
    conv_mfma<64, 64, 3, 3, 1, 8, 8, false><<<dim3(8 * 64), dim3(256), 0, stream>>>(
        A3p, AP + W_A3 + 1 * 110592, g64 + 128, b64 + 128, m64 + 128, v64 + 128, occ1, A2p);
    conv_mfma<64, 64, 3, 3, 1, 8, 8, false><<<dim3(8 * 64), dim3(256), 0, stream>>>(
        A2p, AP + W_A3 + 2 * 110592, g64 + 192, b64 + 192, m64 + 192, v64 + 192, occ1, A3p);
    // L6: 64->64, stride-z 2, D8->4
    conv_mfma<64, 64, 3, 3, 2, 8, 4, false><<<dim3(4 * 64), dim3(256), 0, stream>>>(
        A3p, AP + W_A3 + 3 * 110592, g64 + 256, b64 + 256, m64 + 256, v64 + 256, occ2, A0p);
    // L7..L9: 64->64, D4
    conv_mfma<64, 64, 3, 3, 1, 4, 4, false><<<dim3(4 * 64), dim3(256), 0, stream>>>(
        A0p, AP + W_A3 + 4 * 110592, g64 + 320, b64 + 320, m64 + 320, v64 + 320, occ2, A1p);
    conv_mfma<64, 64, 3, 3, 1, 4, 4, false><<<dim3(4 * 64), dim3(256), 0, stream>>>(
        A1p, AP + W_A3 + 5 * 110592, g64 + 384, b64 + 384, m64 + 384, v64 + 384, occ2, A0p);
    conv_mfma<64, 64, 3, 3, 1, 4, 4, false><<<dim3(4 * 64), dim3(256), 0, stream>>>(
        A0p, AP + W_A3 + 6 * 110592, g64 + 448, b64 + 448, m64 + 448, v64 + 448, occ2, A1p);
    // L10: 64->64, kernel (3,1,1), stride-z 2, D4->2, f32 out -> d_out
    conv_mfma<64, 64, 3, 1, 2, 4, 2, true><<<dim3(2 * 64), dim3(256), 0, stream>>>(
        A1p, AP + W_A10, g64 + 512, b64 + 512, m64 + 512, v64 + 512, occ3, out_f);
}